// Round 6
// baseline (672.255 us; speedup 1.0000x reference)
//
#include <hip/hip_runtime.h>
#include <hip/hip_bf16.h>

typedef unsigned short u16;
typedef __bf16 bf16x8 __attribute__((ext_vector_type(8)));
typedef float f32x4 __attribute__((ext_vector_type(4)));

#define H_DIM 2048
#define I_DIM 1408
#define T_TOK 1024
#define NEXP 8
#define LS 40  // fallback-path LDS stride

__device__ __forceinline__ u16 f2bf(float f) {
    union { float f; unsigned u; } v; v.f = f;
    unsigned r = v.u + 0x7FFFu + ((v.u >> 16) & 1u);  // RNE
    return (u16)(r >> 16);
}
__device__ __forceinline__ unsigned pack2(float a, float b) {
    float2 t; t.x = a; t.y = b;
    __hip_bfloat162 h = __float22bfloat162_rn(t);  // v_cvt_pk_bf16_f32
    union { __hip_bfloat162 h; unsigned u; } v; v.h = h;
    return v.u;
}
__device__ __forceinline__ uint2 pack4(float4 f) {
    uint2 r; r.x = pack2(f.x, f.y); r.y = pack2(f.z, f.w); return r;
}
// build a bf16x8 MFMA fragment from 8 fp32 (two f32x4), order-preserving
__device__ __forceinline__ bf16x8 cvt8(f32x4 a, f32x4 b) {
    union { uint4 u; bf16x8 v; } r;
    r.u.x = pack2(a[0], a[1]); r.u.y = pack2(a[2], a[3]);
    r.u.z = pack2(b[0], b[1]); r.u.w = pack2(b[2], b[3]);
    return r.v;
}
__device__ __forceinline__ void g2l16(const void* g, void* l) {
    __builtin_amdgcn_global_load_lds((const __attribute__((address_space(1))) void*)g,
                                     (__attribute__((address_space(3))) void*)l, 16, 0, 0);
}

// ============ router + x->bf16 convert ============
__global__ __launch_bounds__(256)
void router_x_kernel(const float* __restrict__ x, const float* __restrict__ gw,
                     u16* __restrict__ xb,
                     int* __restrict__ counts, int* __restrict__ tok,
                     float* __restrict__ tw, unsigned* __restrict__ tslot) {
    int wave = threadIdx.x >> 6, lane = threadIdx.x & 63;
    int t = blockIdx.x * 4 + wave;
    const float4* xr = (const float4*)(x + (size_t)t * H_DIM);
    const float4* gw4 = (const float4*)gw;
    uint2* xbr = (uint2*)(xb + (size_t)t * H_DIM);
    float acc[NEXP];
#pragma unroll
    for (int e = 0; e < NEXP; e++) acc[e] = 0.f;
#pragma unroll
    for (int j = 0; j < 8; j++) {
        int c = lane + j * 64;
        float4 xv = xr[c];
        xbr[c] = pack4(xv);
#pragma unroll
        for (int e = 0; e < NEXP; e++) {
            float4 gv = gw4[e * 512 + c];
            acc[e] += xv.x * gv.x + xv.y * gv.y + xv.z * gv.z + xv.w * gv.w;
        }
    }
#pragma unroll
    for (int e = 0; e < NEXP; e++) {
#pragma unroll
        for (int off = 32; off > 0; off >>= 1) acc[e] += __shfl_xor(acc[e], off);
    }
    if (lane == 0) {
        int i0 = 0; float v0 = acc[0];
#pragma unroll
        for (int e = 1; e < NEXP; e++) if (acc[e] > v0) { v0 = acc[e]; i0 = e; }
        int i1 = -1; float v1 = -3.0e38f;
#pragma unroll
        for (int e = 0; e < NEXP; e++) if (e != i0 && acc[e] > v1) { v1 = acc[e]; i1 = e; }
        float ex = __expf(v1 - v0);
        float w0 = 1.f / (1.f + ex);
        float w1 = 1.f - w0;
        int s0 = atomicAdd(&counts[i0], 1);
        tok[i0 * T_TOK + s0] = t; tw[i0 * T_TOK + s0] = w0;
        tslot[t * 2] = ((unsigned)i0 << 16) | (unsigned)s0;
        int s1 = atomicAdd(&counts[i1], 1);
        tok[i1 * T_TOK + s1] = t; tw[i1 * T_TOK + s1] = w1;
        tslot[t * 2 + 1] = ((unsigned)i1 << 16) | (unsigned)s1;
    }
}

// ============ gate+up GEMM, direct fp32 weights ============
// Block 64M x 128N, BK=32, 4 waves each 64Mx32N. A (x) bf16 in LDS; G/U fp32 in LDS,
// converted to bf16 fragments at read time. XCD-aware remap: 4 M-tiles of one
// (expert, n-slab) land on the same XCD (i&7) at consecutive queue slots -> the
// 2 MB fp32 weight slab stays in that XCD's 4 MB L2 across its 4 consumers.
__global__ __launch_bounds__(256, 3)
void gate_up_fd(const u16* __restrict__ xb,
                const float* __restrict__ egw, const float* __restrict__ euw,
                const float* __restrict__ sgw, const float* __restrict__ suw,
                const int* __restrict__ counts, const int* __restrict__ tok,
                const float* __restrict__ tw,
                u16* __restrict__ h_r, u16* __restrict__ h_s) {
    __shared__ u16  lA[64 * 32];     // 4 KB bf16
    __shared__ float lG[128 * 32];   // 16 KB fp32
    __shared__ float lU[128 * 32];   // 16 KB fp32

    int i = blockIdx.x;
    int m_lo = (i >> 3) & 3;
    int group = ((i >> 5) << 3) | (i & 7);   // same group -> same XCD, adjacent slots
    if (group >= 396) return;                // 9 eq * 11 n * 4 m_hi
    int eq = group / 44;
    int rem = group - eq * 44;
    int n0 = (rem >> 2) * 128;
    int m = (rem & 3) * 4 + m_lo;

    bool routed = (eq < NEXP);
    int cnt, hbase; const float *Wg, *Wu; u16* hout;
    if (routed) {
        cnt = counts[eq];
        int p = 0;
#pragma unroll
        for (int ii = 0; ii < NEXP; ii++) { int c = counts[ii]; if (ii < eq) p += c; }
        hbase = p;
        Wg = egw + (size_t)eq * I_DIM * H_DIM;
        Wu = euw + (size_t)eq * I_DIM * H_DIM;
        hout = h_r;
    } else { cnt = T_TOK; hbase = 0; Wg = sgw; Wu = suw; hout = h_s; }
    int m0 = m * 64;
    if (m0 >= cnt) return;

    int tid = threadIdx.x, lane = tid & 63, w = tid >> 6;

    // A staging: 64 rows x 4 chunks(16B of bf16); stored chunk sc holds global sc^(row&3)
    int La = w * 64 + lane;
    int arow = La >> 2;
    int agc = (La & 3) ^ (arow & 3);
    int trow = m0 + arow; if (trow > cnt - 1) trow = cnt - 1;
    int tix = routed ? tok[eq * T_TOK + trow] : trow;
    const u16* aptr = xb + (size_t)tix * H_DIM + agc * 8;
    u16* adst = &lA[(w * 64) * 8];

    // G/U staging: 128 rows x 8 chunks(16B of fp32); stored sc holds global sc^((row&3)<<1)
    const float* gptr[4]; const float* uptr[4]; float* gdst[4]; float* udst[4];
#pragma unroll
    for (int j = 0; j < 4; j++) {
        int L = w * 256 + j * 64 + lane;
        int row = L >> 3;
        int gc = (L & 7) ^ ((row & 3) << 1);
        gptr[j] = Wg + (size_t)(n0 + row) * H_DIM + gc * 4;
        uptr[j] = Wu + (size_t)(n0 + row) * H_DIM + gc * 4;
        gdst[j] = &lG[(w * 256 + j * 64) * 4];
        udst[j] = &lU[(w * 256 + j * 64) * 4];
    }

    f32x4 zero = {0.f, 0.f, 0.f, 0.f};
    f32x4 accg[4][2], accu[4][2];
#pragma unroll
    for (int a = 0; a < 4; a++)
#pragma unroll
        for (int b = 0; b < 2; b++) { accg[a][b] = zero; accu[a][b] = zero; }

    int r16 = lane & 15, q = lane >> 4;
    int offa[4], offg[2];
#pragma unroll
    for (int mi = 0; mi < 4; mi++) {
        int row = mi * 16 + r16;
        offa[mi] = row * 32 + (q ^ (row & 3)) * 8;          // u16 index
    }
#pragma unroll
    for (int ni = 0; ni < 2; ni++) {
        int row = w * 32 + ni * 16 + r16;
        offg[ni] = row * 32 + ((2 * q) ^ ((row & 3) << 1)) * 4;  // float index
    }

    for (int k0 = 0; k0 < H_DIM; k0 += 32) {
        g2l16(aptr + k0, adst);
#pragma unroll
        for (int j = 0; j < 4; j++) { g2l16(gptr[j] + k0, gdst[j]); g2l16(uptr[j] + k0, udst[j]); }
        __syncthreads();
        bf16x8 af[4], gf[2], uf[2];
#pragma unroll
        for (int mi = 0; mi < 4; mi++) af[mi] = *(const bf16x8*)&lA[offa[mi]];
#pragma unroll
        for (int ni = 0; ni < 2; ni++) {
            const f32x4* pg = (const f32x4*)&lG[offg[ni]];
            gf[ni] = cvt8(pg[0], pg[1]);
            const f32x4* pu = (const f32x4*)&lU[offg[ni]];
            uf[ni] = cvt8(pu[0], pu[1]);
        }
#pragma unroll
        for (int mi = 0; mi < 4; mi++)
#pragma unroll
            for (int ni = 0; ni < 2; ni++) {
                accg[mi][ni] = __builtin_amdgcn_mfma_f32_16x16x32_bf16(af[mi], gf[ni], accg[mi][ni], 0, 0, 0);
                accu[mi][ni] = __builtin_amdgcn_mfma_f32_16x16x32_bf16(af[mi], uf[ni], accu[mi][ni], 0, 0, 0);
            }
        __syncthreads();
    }

    // epilogue: C/D col=lane&15, row=(lane>>4)*4+reg
#pragma unroll
    for (int mi = 0; mi < 4; mi++) {
#pragma unroll
        for (int r = 0; r < 4; r++) {
            int row = mi * 16 + q * 4 + r;
            int gr = m0 + row;
            if (gr < cnt) {
                float wt = routed ? tw[eq * T_TOK + gr] : 1.0f;
                u16* hrow = hout + (size_t)(hbase + gr) * I_DIM + n0 + w * 32;
#pragma unroll
                for (int ni = 0; ni < 2; ni++) {
                    float g = accg[mi][ni][r], u = accu[mi][ni][r];
                    hrow[ni * 16 + r16] = f2bf((g / (1.f + __expf(-g))) * u * wt);
                }
            }
        }
    }
}

// ============ down GEMM, direct fp32 weights: 64Mx128N, BK=64, fp32 stores to y ============
__global__ __launch_bounds__(256, 3)
void down_fd(const u16* __restrict__ h_r, const u16* __restrict__ h_s,
             const float* __restrict__ edw, const float* __restrict__ sdw,
             const int* __restrict__ counts, const int* __restrict__ tok,
             float* __restrict__ y_r, float* __restrict__ y_s) {
    __shared__ u16  lA[64 * 64];     // 8 KB bf16 (h)
    __shared__ float lB[128 * 64];   // 32 KB fp32 (Wd)

    int i = blockIdx.x;                       // grid 2304 = 72*32 exact
    int m_lo = (i >> 3) & 3;
    int group = ((i >> 5) << 3) | (i & 7);    // 0..575 = 9 eq * 16 n * 4 m_hi
    int eq = group >> 6;
    int rem = group & 63;
    int n0 = (rem >> 2) * 128;
    int m = (rem & 3) * 4 + m_lo;

    bool routed = (eq < NEXP);
    int cnt, hbase; const float* Wd; const u16* hin;
    if (routed) {
        cnt = counts[eq];
        int p = 0;
#pragma unroll
        for (int ii = 0; ii < NEXP; ii++) { int c = counts[ii]; if (ii < eq) p += c; }
        hbase = p;
        Wd = edw + (size_t)eq * H_DIM * I_DIM;
        hin = h_r;
    } else { cnt = T_TOK; hbase = 0; Wd = sdw; hin = h_s; }
    int m0 = m * 64;
    if (m0 >= cnt) return;

    int tid = threadIdx.x, lane = tid & 63, w = tid >> 6;

    // A staging: 64 rows x 8 chunks bf16; stored sc holds global sc^(row&7)  (round-5 layout)
    const u16* aptr[2]; u16* adst[2];
#pragma unroll
    for (int j = 0; j < 2; j++) {
        int L = w * 128 + j * 64 + lane;
        int row = L >> 3;
        int gc = (L & 7) ^ (row & 7);
        int hr = m0 + row; if (hr > cnt - 1) hr = cnt - 1;
        aptr[j] = hin + (size_t)(hbase + hr) * I_DIM + gc * 8;
        adst[j] = &lA[(w * 128 + j * 64) * 8];
    }
    // B staging: 128 rows x 16 chunks fp32; stored sc holds global sc^((row&7)<<1)
    const float* bptr[8]; float* bdst[8];
#pragma unroll
    for (int j = 0; j < 8; j++) {
        int L = w * 512 + j * 64 + lane;
        int row = L >> 4;
        int gc = (L & 15) ^ ((row & 7) << 1);
        bptr[j] = Wd + (size_t)(n0 + row) * I_DIM + gc * 4;
        bdst[j] = &lB[(w * 512 + j * 64) * 4];
    }

    f32x4 zero = {0.f, 0.f, 0.f, 0.f};
    f32x4 acc[4][2];
#pragma unroll
    for (int a = 0; a < 4; a++)
#pragma unroll
        for (int b = 0; b < 2; b++) acc[a][b] = zero;

    int r16 = lane & 15, q = lane >> 4;

    for (int k0 = 0; k0 < I_DIM; k0 += 64) {  // 22 iters
#pragma unroll
        for (int j = 0; j < 2; j++) g2l16(aptr[j] + k0, adst[j]);
#pragma unroll
        for (int j = 0; j < 8; j++) g2l16(bptr[j] + k0, bdst[j]);
        __syncthreads();
#pragma unroll
        for (int kh = 0; kh < 2; kh++) {
            bf16x8 af[4], bfr[2];
#pragma unroll
            for (int mi = 0; mi < 4; mi++) {
                int row = mi * 16 + r16;
                int ch = (kh * 4 + q) ^ (row & 7);
                af[mi] = *(const bf16x8*)&lA[row * 64 + ch * 8];
            }
#pragma unroll
            for (int ni = 0; ni < 2; ni++) {
                int row = w * 32 + ni * 16 + r16;
                int ch = (2 * (kh * 4 + q)) ^ ((row & 7) << 1);
                const f32x4* pb = (const f32x4*)&lB[row * 64 + ch * 4];
                bfr[ni] = cvt8(pb[0], pb[1]);
            }
#pragma unroll
            for (int mi = 0; mi < 4; mi++)
#pragma unroll
                for (int ni = 0; ni < 2; ni++)
                    acc[mi][ni] = __builtin_amdgcn_mfma_f32_16x16x32_bf16(af[mi], bfr[ni], acc[mi][ni], 0, 0, 0);
        }
        __syncthreads();
    }

#pragma unroll
    for (int mi = 0; mi < 4; mi++) {
#pragma unroll
        for (int r = 0; r < 4; r++) {
            int row = mi * 16 + q * 4 + r;
            int gr = m0 + row;
            if (gr < cnt) {
                float* yrow = (routed ? y_r + (size_t)(hbase + gr) * H_DIM
                                      : y_s + (size_t)gr * H_DIM) + n0 + w * 32;
#pragma unroll
                for (int ni = 0; ni < 2; ni++)
                    yrow[ni * 16 + r16] = acc[mi][ni][r];
            }
        }
    }
}

// ============ reduce: out[t] = y_s[t] + y_r[slot0(t)] + y_r[slot1(t)] ============
__global__ __launch_bounds__(256)
void reduce_kernel(const int* __restrict__ counts, const unsigned* __restrict__ tslot,
                   const float* __restrict__ y_r, const float* __restrict__ y_s,
                   float* __restrict__ out) {
    int t = blockIdx.x;
    int pre[NEXP]; int run = 0;
#pragma unroll
    for (int i = 0; i < NEXP; i++) { pre[i] = run; run += counts[i]; }
    unsigned t0 = tslot[t * 2], t1 = tslot[t * 2 + 1];
    int r0 = pre[t0 >> 16] + (int)(t0 & 0xffffu);
    int r1 = pre[t1 >> 16] + (int)(t1 & 0xffffu);
    const float4* ys = (const float4*)(y_s + (size_t)t * H_DIM);
    const float4* a0 = (const float4*)(y_r + (size_t)r0 * H_DIM);
    const float4* a1 = (const float4*)(y_r + (size_t)r1 * H_DIM);
    float4* o = (float4*)(out + (size_t)t * H_DIM);
#pragma unroll
    for (int j = 0; j < 2; j++) {
        int c = threadIdx.x + j * 256;
        float4 s = ys[c], b0 = a0[c], b1 = a1[c];
        float4 r;
        r.x = s.x + b0.x + b1.x; r.y = s.y + b0.y + b1.y;
        r.z = s.z + b0.z + b1.z; r.w = s.w + b0.w + b1.w;
        o[c] = r;
    }
}

// ================= FALLBACK PATH (fp32, only if ws too small) =================
__global__ __launch_bounds__(256)
void router_kernel(const float* __restrict__ x, const float* __restrict__ gw,
                   int* __restrict__ counts, int* __restrict__ tok, float* __restrict__ tw) {
    int wave = threadIdx.x >> 6;
    int lane = threadIdx.x & 63;
    int t = blockIdx.x * 4 + wave;
    const float* xr = x + (size_t)t * H_DIM;
    float acc[NEXP];
#pragma unroll
    for (int e = 0; e < NEXP; e++) acc[e] = 0.f;
    for (int h = lane; h < H_DIM; h += 64) {
        float xv = xr[h];
#pragma unroll
        for (int e = 0; e < NEXP; e++) acc[e] += xv * gw[e * H_DIM + h];
    }
#pragma unroll
    for (int e = 0; e < NEXP; e++) {
#pragma unroll
        for (int off = 32; off > 0; off >>= 1) acc[e] += __shfl_xor(acc[e], off);
    }
    if (lane == 0) {
        int i0 = 0; float v0 = acc[0];
#pragma unroll
        for (int e = 1; e < NEXP; e++) if (acc[e] > v0) { v0 = acc[e]; i0 = e; }
        int i1 = -1; float v1 = -3.0e38f;
#pragma unroll
        for (int e = 0; e < NEXP; e++) if (e != i0 && acc[e] > v1) { v1 = acc[e]; i1 = e; }
        float ex = __expf(v1 - v0);
        float w0 = 1.f / (1.f + ex);
        float w1 = 1.f - w0;
        int s0 = atomicAdd(&counts[i0], 1);
        tok[i0 * T_TOK + s0] = t; tw[i0 * T_TOK + s0] = w0;
        int s1 = atomicAdd(&counts[i1], 1);
        tok[i1 * T_TOK + s1] = t; tw[i1 * T_TOK + s1] = w1;
    }
}

__global__ __launch_bounds__(256, 2)
void gate_up_f32(const float* __restrict__ x,
                 const float* __restrict__ egw, const float* __restrict__ euw,
                 const float* __restrict__ sgw, const float* __restrict__ suw,
                 const int* __restrict__ counts, const int* __restrict__ tok,
                 const float* __restrict__ tw,
                 u16* __restrict__ h_r, u16* __restrict__ h_s) {
    __shared__ u16 lA[64 * LS];
    __shared__ u16 lG[128 * LS];
    __shared__ u16 lU[128 * LS];
    int e = blockIdx.z;
    bool routed = (e < NEXP);
    int cnt, hbase; const float *Wg, *Wu; u16* hout;
    if (routed) {
        cnt = counts[e];
        int p = 0;
#pragma unroll
        for (int i = 0; i < NEXP; i++) { int c = counts[i]; if (i < e) p += c; }
        hbase = p;
        Wg = egw + (size_t)e * I_DIM * H_DIM; Wu = euw + (size_t)e * I_DIM * H_DIM; hout = h_r;
    } else { cnt = T_TOK; hbase = 0; Wg = sgw; Wu = suw; hout = h_s; }
    int m0 = blockIdx.y * 64;
    if (m0 >= cnt) return;
    int n0 = blockIdx.x * 128;
    int tid = threadIdx.x, lane = tid & 63, w = tid >> 6;
    const float* ap[2]; int sa[2];
#pragma unroll
    for (int i = 0; i < 2; i++) {
        int slot = tid + i * 256;
        int row = slot >> 3, c4 = slot & 7;
        sa[i] = row * LS + c4 * 4;
        int trow = m0 + row; if (trow > cnt - 1) trow = cnt - 1;
        int tix = routed ? tok[e * T_TOK + trow] : trow;
        ap[i] = x + (size_t)tix * H_DIM + c4 * 4;
    }
    const float* gp[4]; const float* up[4]; int sg[4];
#pragma unroll
    for (int i = 0; i < 4; i++) {
        int slot = tid + i * 256;
        int row = slot >> 3, c4 = slot & 7;
        sg[i] = row * LS + c4 * 4;
        gp[i] = Wg + (size_t)(n0 + row) * H_DIM + c4 * 4;
        up[i] = Wu + (size_t)(n0 + row) * H_DIM + c4 * 4;
    }
    f32x4 zero = {0.f, 0.f, 0.f, 0.f};
    f32x4 accg[4][2], accu[4][2];
#pragma unroll
    for (int a = 0; a < 4; a++)
#pragma unroll
        for (int b = 0; b < 2; b++) { accg[a][b] = zero; accu[a][b] = zero; }
    int r16 = lane & 15, kq = lane >> 4;
    float4 ra[2], rg[4], ru[4];
#pragma unroll
    for (int i = 0; i < 2; i++) ra[i] = *(const float4*)(ap[i]);
#pragma unroll
    for (int i = 0; i < 4; i++) { rg[i] = *(const float4*)(gp[i]); ru[i] = *(const float4*)(up[i]); }
    for (int k0 = 0; k0 < H_DIM; k0 += 32) {
#pragma unroll
        for (int i = 0; i < 2; i++) *(uint2*)&lA[sa[i]] = pack4(ra[i]);
#pragma unroll
        for (int i = 0; i < 4; i++) { *(uint2*)&lG[sg[i]] = pack4(rg[i]); *(uint2*)&lU[sg[i]] = pack4(ru[i]); }
        __syncthreads();
        if (k0 + 32 < H_DIM) {
            int kn = k0 + 32;
#pragma unroll
            for (int i = 0; i < 2; i++) ra[i] = *(const float4*)(ap[i] + kn);
#pragma unroll
            for (int i = 0; i < 4; i++) { rg[i] = *(const float4*)(gp[i] + kn); ru[i] = *(const float4*)(up[i] + kn); }
        }
        bf16x8 af[4], gf[2], uf[2];
#pragma unroll
        for (int mi = 0; mi < 4; mi++) af[mi] = *(const bf16x8*)&lA[(mi * 16 + r16) * LS + kq * 8];
#pragma unroll
        for (int ni = 0; ni < 2; ni++) {
            gf[ni] = *(const bf16x8*)&lG[(w * 32 + ni * 16 + r16) * LS + kq * 8];
            uf[ni] = *(const bf16x8*)&lU[(w * 32 + ni * 16 + r16) * LS + kq * 8];
        }
#pragma unroll
        for (int mi = 0; mi < 4; mi++)
#pragma unroll
            for (int ni = 0; ni < 2; ni++) {
                accg[mi][ni] = __builtin_amdgcn_mfma_f32_16x16x32_bf16(af[mi], gf[ni], accg[mi][ni], 0, 0, 0);
                accu[mi][ni] = __builtin_amdgcn_mfma_f32_16x16x32_bf16(af[mi], uf[ni], accu[mi][ni], 0, 0, 0);
            }
        __syncthreads();
    }
#pragma unroll
    for (int mi = 0; mi < 4; mi++) {
#pragma unroll
        for (int r = 0; r < 4; r++) {
            int row = mi * 16 + kq * 4 + r;
            int gr = m0 + row;
            if (gr < cnt) {
                float wt = routed ? tw[e * T_TOK + gr] : 1.0f;
                u16* hrow = hout + (size_t)(hbase + gr) * I_DIM + n0 + w * 32;
#pragma unroll
                for (int ni = 0; ni < 2; ni++) {
                    float g = accg[mi][ni][r], u = accu[mi][ni][r];
                    hrow[ni * 16 + r16] = f2bf((g / (1.f + __expf(-g))) * u * wt);
                }
            }
        }
    }
}

__global__ __launch_bounds__(256, 2)
void down_f32(const u16* __restrict__ h_r, const u16* __restrict__ h_s,
              const float* __restrict__ edw, const float* __restrict__ sdw,
              const int* __restrict__ counts, const int* __restrict__ tok,
              float* __restrict__ out) {
    __shared__ u16 lA[64 * LS];
    __shared__ u16 lB[128 * LS];
    int e = blockIdx.z;
    bool routed = (e < NEXP);
    int cnt, hbase; const float* Wd; const u16* hin;
    if (routed) {
        cnt = counts[e];
        int p = 0;
#pragma unroll
        for (int i = 0; i < NEXP; i++) { int c = counts[i]; if (i < e) p += c; }
        hbase = p;
        Wd = edw + (size_t)e * H_DIM * I_DIM; hin = h_r;
    } else { cnt = T_TOK; hbase = 0; Wd = sdw; hin = h_s; }
    int m0 = blockIdx.y * 64;
    if (m0 >= cnt) return;
    int n0 = blockIdx.x * 128;
    int tid = threadIdx.x, lane = tid & 63, w = tid >> 6;
    int arow = tid >> 2, ac8 = tid & 3;
    int hr = m0 + arow; if (hr > cnt - 1) hr = cnt - 1;
    const u16* ap = hin + (size_t)(hbase + hr) * I_DIM + ac8 * 8;
    int sa = arow * LS + ac8 * 8;
    const float* bp[4]; int sb[4];
#pragma unroll
    for (int i = 0; i < 4; i++) {
        int slot = tid + i * 256;
        int row = slot >> 3, c4 = slot & 7;
        bp[i] = Wd + (size_t)(n0 + row) * I_DIM + c4 * 4;
        sb[i] = row * LS + c4 * 4;
    }
    f32x4 zero = {0.f, 0.f, 0.f, 0.f};
    f32x4 acc[4][2];
#pragma unroll
    for (int a = 0; a < 4; a++)
#pragma unroll
        for (int b = 0; b < 2; b++) acc[a][b] = zero;
    int r16 = lane & 15, kq = lane >> 4;
    uint4 ra = *(const uint4*)(ap);
    float4 rb[4];
#pragma unroll
    for (int i = 0; i < 4; i++) rb[i] = *(const float4*)(bp[i]);
    for (int k0 = 0; k0 < I_DIM; k0 += 32) {
        *(uint4*)&lA[sa] = ra;
#pragma unroll
        for (int i = 0; i < 4; i++) *(uint2*)&lB[sb[i]] = pack4(rb[i]);
        __syncthreads();
        if (k0 + 32 < I_DIM) {
            int kn = k0 + 32;
            ra = *(const uint4*)(ap + kn);
#pragma unroll
            for (int i = 0; i < 4; i++) rb[i] = *(const float4*)(bp[i] + kn);
        }
        bf16x8 af[4], bfr[2];
#pragma unroll
        for (int mi = 0; mi < 4; mi++) af[mi] = *(const bf16x8*)&lA[(mi * 16 + r16) * LS + kq * 8];
#pragma unroll
        for (int ni = 0; ni < 2; ni++) bfr[ni] = *(const bf16x8*)&lB[(w * 32 + ni * 16 + r16) * LS + kq * 8];
#pragma unroll
        for (int mi = 0; mi < 4; mi++)
#pragma unroll
            for (int ni = 0; ni < 2; ni++)
                acc[mi][ni] = __builtin_amdgcn_mfma_f32_16x16x32_bf16(af[mi], bfr[ni], acc[mi][ni], 0, 0, 0);
        __syncthreads();
    }
#pragma unroll
    for (int mi = 0; mi < 4; mi++) {
#pragma unroll
        for (int r = 0; r < 4; r++) {
            int row = mi * 16 + kq * 4 + r;
            int gr = m0 + row;
            if (gr < cnt) {
                int t = routed ? tok[e * T_TOK + gr] : gr;
                float* orow = out + (size_t)t * H_DIM + n0 + w * 32;
#pragma unroll
                for (int ni = 0; ni < 2; ni++)
                    atomicAdd(&orow[ni * 16 + r16], acc[mi][ni][r]);
            }
        }
    }
}

extern "C" void kernel_launch(void* const* d_in, const int* in_sizes, int n_in,
                              void* d_out, int out_size, void* d_ws, size_t ws_size,
                              hipStream_t stream) {
    const float* x   = (const float*)d_in[0];
    const float* gw  = (const float*)d_in[1];
    const float* egw = (const float*)d_in[2];
    const float* euw = (const float*)d_in[3];
    const float* edw = (const float*)d_in[4];
    const float* sgw = (const float*)d_in[5];
    const float* suw = (const float*)d_in[6];
    const float* sdw = (const float*)d_in[7];
    float* out = (float*)d_out;

    char* ws = (char*)d_ws;
    int*      counts = (int*)ws;                  // 32 B
    int*      tok    = (int*)(ws + 256);          // 32 KB
    float*    tw     = (float*)(ws + 33024);      // 32 KB
    unsigned* tslot  = (unsigned*)(ws + 65792);   // 8 KB
    u16*      h_r    = (u16*)(ws + 73984);        // 5767168 B
    u16*      h_s    = (u16*)(ws + 5841152);      // 2883584 B
    u16*      xb     = (u16*)(ws + 8724736);      // 4194304 B
    float*    y_r    = (float*)(ws + 12919040);   // 16777216 B
    float*    y_s    = (float*)(ws + 29696256);   // 8388608 B -> end 38084864

    hipMemsetAsync(counts, 0, 32, stream);

    const size_t NEED = 38084864ull;
    if (ws_size >= NEED) {
        router_x_kernel<<<256, 256, 0, stream>>>(x, gw, xb, counts, tok, tw, tslot);
        gate_up_fd<<<1600, 256, 0, stream>>>(xb, egw, euw, sgw, suw, counts, tok, tw, h_r, h_s);
        down_fd<<<2304, 256, 0, stream>>>(h_r, h_s, edw, sdw, counts, tok, y_r, y_s);
        reduce_kernel<<<1024, 256, 0, stream>>>(counts, tslot, y_r, y_s, out);
    } else {
        hipMemsetAsync(out, 0, (size_t)T_TOK * H_DIM * sizeof(float), stream);
        router_kernel<<<256, 256, 0, stream>>>(x, gw, counts, tok, tw);
        gate_up_f32<<<dim3(11, 16, 9), 256, 0, stream>>>(x, egw, euw, sgw, suw, counts, tok, tw, h_r, h_s);
        down_f32<<<dim3(16, 16, 9), 256, 0, stream>>>(h_r, h_s, edw, sdw, counts, tok, out);
    }
}